// Round 1
// 669.100 us; speedup vs baseline: 1.0578x; 1.0578x over previous
//
#include <hip/hip_runtime.h>
#include <math.h>

#define NN 500
#define BB 512
#define BGRP 4            // batch rows per block (amortizes WU reads 4x)
#define NCHUNK 10         // j-dimension split (50 rows per block)
#define JCH (NN / NCHUNK) // 50
#define NPAIR (NN / 2)    // 250 i-pairs per row

using f2 = __attribute__((ext_vector_type(2))) float;

// ---------------- prep: bit-exact f32 threshold + interleaved (W,U*) table ---
// Emulate numpy's float32 pipeline with correctly-rounded f32 ops:
//   uc -> l1=f32(log uc); s=f32(1-uc); l2=f32(log s);
//   z=f32(la+f32(l1-l2)); y=f32(1/f32(1+f32(exp(-z)))); decision = y > 0.5f
__device__ __forceinline__ bool np_decision(float laf, float v) {
    float l1 = (float)log((double)v);
    float s  = 1.0f - v;
    float l2 = (float)log((double)s);
    float logistic = l1 - l2;
    float z  = laf + logistic;
    float e  = (float)exp(-(double)z);
    float d  = 1.0f + e;
    float y  = 1.0f / d;
    return y > 0.5f;
}

// WU[j*NN+i] = { Wt, Ustar } where Wt = (i==j ? 0 : W[i][j]) and Ustar is the
// smallest f32 uc in [LO,HI] whose emulated-f32 decision is TRUE (monotone).
// Window narrowed to +/-32 ulps around the double-precision threshold
// prediction (empirically within a few ulps); wide-range fallback keeps
// correctness if the prediction misses.
__global__ void prep_kernel(const float* __restrict__ la,
                            const float* __restrict__ W,
                            float2* __restrict__ WU) {
    int idx = blockIdx.x * blockDim.x + threadIdx.x;
    if (idx >= NN * NN) return;
    int j = idx / NN;
    int i = idx - j * NN;
    float laf = la[idx];

    const float LO = 1e-6f;
    const float HI = (float)(1.0 - 1e-6);

    float U;
    if (!np_decision(laf, HI)) {
        U = __builtin_inff();               // never true
    } else if (np_decision(laf, LO)) {
        U = 0.0f;                           // always true
    } else {
        // invariant: decision(lo)==false, decision(hi)==true
        unsigned lo = __float_as_uint(LO);
        unsigned hi = __float_as_uint(HI);
        double T  = 1.0 / (1.0 + exp((double)laf));
        float  Tf = fminf(fmaxf((float)T, LO), HI);
        unsigned g = __float_as_uint(Tf);
        unsigned a = (g > lo + 32u) ? g - 32u : lo;
        unsigned b = (g + 32u < hi) ? g + 32u : hi;
        if (a > lo) {
            if (np_decision(laf, __uint_as_float(a))) hi = a; else lo = a;
        }
        if (b > lo && b < hi) {
            if (np_decision(laf, __uint_as_float(b))) hi = b; else lo = b;
        }
        while (hi - lo > 1u) {
            unsigned mid = lo + (hi - lo) / 2u;
            if (np_decision(laf, __uint_as_float(mid))) hi = mid; else lo = mid;
        }
        U = __uint_as_float(hi);
    }
    float w = (i == j) ? 0.0f : W[i * NN + j];
    WU[idx] = make_float2(w, U);
}

// ---------------- fused: partial masked matvec, 4 batch rows per block -------
// grid = (BB/BGRP) * NCHUNK = 1280 blocks (5 blocks/CU -> 20 waves/CU).
// Block (bg, c) streams u[b0..b0+3, c*50 .. c*50+50, :] with non-temporal
// loads (no reuse; keeps WU resident in L2). One float4 WU load serves 4
// batch rows -> WU L2 traffic 1.02 GB -> 256 MB.
// Clamps removed: U* already encodes clamp semantics (see prep).
__global__ __launch_bounds__(256) void fused_kernel(
        const float* __restrict__ x,
        const float* __restrict__ u,
        const float4* __restrict__ WU4,   // (w,U*) pairs, 2 columns per float4
        float* __restrict__ P) {
    __shared__ float xs[BGRP][JCH];
    const int bid = blockIdx.x;
    const int bg = bid / NCHUNK;
    const int c  = bid - bg * NCHUNK;
    const int b0 = bg * BGRP;
    const int j0 = c * JCH;
    const int t = threadIdx.x;
    if (t < BGRP * JCH) {
        int bl = t / JCH;
        int j  = t - bl * JCH;
        xs[bl][j] = x[(b0 + bl) * NN + j0 + j];
    }
    __syncthreads();
    if (t >= NPAIR) return;

    const f2* __restrict__ u0 = (const f2*)(u + (size_t)(b0 + 0) * NN * NN);
    const f2* __restrict__ u1 = (const f2*)(u + (size_t)(b0 + 1) * NN * NN);
    const f2* __restrict__ u2 = (const f2*)(u + (size_t)(b0 + 2) * NN * NN);
    const f2* __restrict__ u3 = (const f2*)(u + (size_t)(b0 + 3) * NN * NN);

    float a00 = 0.0f, a01 = 0.0f, a10 = 0.0f, a11 = 0.0f;
    float a20 = 0.0f, a21 = 0.0f, a30 = 0.0f, a31 = 0.0f;
    int k = j0 * NPAIR + t;
#pragma unroll 5
    for (int j = 0; j < JCH; ++j, k += NPAIR) {
        float4 wv = WU4[k];                        // (w0, U0, w1, U1) — L2
        f2 v0 = __builtin_nontemporal_load(u0 + k);
        f2 v1 = __builtin_nontemporal_load(u1 + k);
        f2 v2 = __builtin_nontemporal_load(u2 + k);
        f2 v3 = __builtin_nontemporal_load(u3 + k);
        float x0 = xs[0][j], x1 = xs[1][j], x2 = xs[2][j], x3 = xs[3][j];
        if (v0.x >= wv.y) a00 += wv.x * x0;
        if (v0.y >= wv.w) a01 += wv.z * x0;
        if (v1.x >= wv.y) a10 += wv.x * x1;
        if (v1.y >= wv.w) a11 += wv.z * x1;
        if (v2.x >= wv.y) a20 += wv.x * x2;
        if (v2.y >= wv.w) a21 += wv.z * x2;
        if (v3.x >= wv.y) a30 += wv.x * x3;
        if (v3.y >= wv.w) a31 += wv.z * x3;
    }
    float* Pb = P + ((size_t)c * BB + b0) * NN;
    ((float2*)(Pb + 0 * NN))[t] = make_float2(a00, a01);
    ((float2*)(Pb + 1 * NN))[t] = make_float2(a10, a11);
    ((float2*)(Pb + 2 * NN))[t] = make_float2(a20, a21);
    ((float2*)(Pb + 3 * NN))[t] = make_float2(a30, a31);
}

// ---------------- reduce: sum 10 partials + tanh, float4-vectorized ----------
__global__ __launch_bounds__(256) void reduce_kernel(const float* __restrict__ P,
                                                     float* __restrict__ out) {
    int n4 = blockIdx.x * blockDim.x + threadIdx.x;
    if (n4 >= BB * NN / 4) return;
    const int S = BB * NN;
    float4 s = ((const float4*)P)[n4];
#pragma unroll
    for (int cc = 1; cc < NCHUNK; ++cc) {
        float4 p = ((const float4*)(P + (size_t)cc * S))[n4];
        s.x += p.x; s.y += p.y; s.z += p.z; s.w += p.w;
    }
    ((float4*)out)[n4] = make_float4(tanhf(s.x), tanhf(s.y), tanhf(s.z), tanhf(s.w));
}

extern "C" void kernel_launch(void* const* d_in, const int* in_sizes, int n_in,
                              void* d_out, int out_size, void* d_ws, size_t ws_size,
                              hipStream_t stream) {
    const float* x  = (const float*)d_in[0];   // [B, N]
    const float* la = (const float*)d_in[1];   // [N, N]
    const float* W  = (const float*)d_in[2];   // [N, N]
    const float* u  = (const float*)d_in[3];   // [B, N, N]
    float* out = (float*)d_out;                // [B, N]

    float2* WU = (float2*)d_ws;                                        // 2,000,000 B
    float*  P  = (float*)((char*)d_ws + (size_t)NN * NN * sizeof(float2)); // 10,240,000 B

    int prep_blocks = (NN * NN + 255) / 256;
    prep_kernel<<<prep_blocks, 256, 0, stream>>>(la, W, WU);
    fused_kernel<<<(BB / BGRP) * NCHUNK, 256, 0, stream>>>(x, u, (const float4*)WU, P);
    reduce_kernel<<<(BB * NN / 4 + 255) / 256, 256, 0, stream>>>(P, out);
}